// Round 1
// 1268.499 us; speedup vs baseline: 1.0617x; 1.0617x over previous
//
#include <hip/hip_runtime.h>
#include <hip/hip_bf16.h>
#include <math.h>

// ---- problem constants ----
#define BB     16
#define HH     64
#define WWID   64
#define CCH    512
#define HEADS  16
#define NTOK   64
#define DDIM   32
#define NWIN   64
#define LL     (HH*WWID)       // 4096
#define MTOT   (BB*LL)         // 65536 rows
#define BWIN   (BB*NWIN)       // 1024 windows
#define HIDN   2048
#define SHIFT_ 4

typedef unsigned short u16;
using bf16x8 = __attribute__((ext_vector_type(8))) short;   // 8 bf16 (4 VGPRs)
using f32x4  = __attribute__((ext_vector_type(4))) float;
using f32x16 = __attribute__((ext_vector_type(16))) float;

__device__ __forceinline__ u16 f2bf(float f) {
  union { float f; unsigned u; } v; v.f = f;
  unsigned r = v.u + 0x7fffu + ((v.u >> 16) & 1u);   // RNE
  return (u16)(r >> 16);
}
__device__ __forceinline__ float bf2f(unsigned h) {
  union { unsigned u; float f; } v; v.u = h << 16;
  return v.f;
}

__device__ __forceinline__ void gload16(const void* g, void* l) {
  __builtin_amdgcn_global_load_lds((const __attribute__((address_space(1))) void*)g,
                                   (__attribute__((address_space(3))) void*)l, 16, 0, 0);
}

// shifted-window mapping: windowed token (b_, n) -> original row index in x
__device__ __forceinline__ int win2orig(int b_, int n) {
  int b = b_ >> 6, wi = b_ & 63;
  int hs = (wi >> 3) * 8 + (n >> 3);
  int ws = (wi & 7) * 8 + (n & 7);
  int hq = (hs + SHIFT_) & 63;
  int wq = (ws + SHIFT_) & 63;
  return b * LL + hq * WWID + wq;
}

// ---------------- tiny setup kernels ----------------
__global__ void cvt_k(const float* __restrict__ s, u16* __restrict__ d, int n) {
  int i = blockIdx.x * 256 + threadIdx.x;
  if (i < n) d[i] = f2bf(s[i]);
}

__global__ void cpb_k(const float* __restrict__ ct, const float* __restrict__ w1,
                      const float* __restrict__ b1, const float* __restrict__ w2,
                      float* __restrict__ t2) {
  int t = blockIdx.x * 256 + threadIdx.x;
  if (t >= 225 * 16) return;
  int rr = t >> 4, h = t & 15;
  float c0 = ct[rr * 2], c1 = ct[rr * 2 + 1];
  float acc = 0.f;
  for (int j = 0; j < 512; j++) {
    float hv = fmaxf(w1[j * 2] * c0 + w1[j * 2 + 1] * c1 + b1[j], 0.f);
    acc += hv * w2[h * 512 + j];
  }
  t2[t] = acc;
}

__global__ void bias_k(const float* __restrict__ t2, const int* __restrict__ rpi,
                       float* __restrict__ b16) {
  int t = blockIdx.x * 256 + threadIdx.x;   // h*4096 + n*64 + m
  int nm = t & 4095;
  int h = t >> 12;
  float v = t2[rpi[nm] * 16 + h];
  b16[t] = 16.0f / (1.0f + __expf(-v));
}

__global__ void scale_k(const float* __restrict__ ls, float* __restrict__ sc) {
  int t = threadIdx.x;
  if (t < HEADS) sc[t] = __expf(fminf(ls[t], 4.6051701859880914f)); // ln(100)
}

// x (fp32) -> xw (bf16) in shifted-window token order [b_*64+n][512]
__global__ __launch_bounds__(256) void xw_k(const float* __restrict__ x, u16* __restrict__ xw) {
  int t = blockIdx.x * 256 + threadIdx.x;
  int row = t >> 6;
  int col = (t & 63) * 8;
  const float* src = x + (size_t)win2orig(row >> 6, row & 63) * CCH + col;
  float4 a = *(const float4*)src;
  float4 b = *(const float4*)(src + 4);
  u16 o[8] = {f2bf(a.x), f2bf(a.y), f2bf(a.z), f2bf(a.w),
              f2bf(b.x), f2bf(b.y), f2bf(b.z), f2bf(b.w)};
  *(uint4*)(xw + (size_t)row * CCH + col) = *(const uint4*)o;
}

// ---------------- MFMA GEMM, 256x128 block tile, 32x32x16 MFMA ----------------
// A bf16 [M][K], B bf16 [N][K] -> C = A @ B^T.  4 waves, wave tile 128x64.
// Operands SWAPPED in the MFMA (mfma(b,a)) so acc holds C^T tiles:
//   lane (l31) owns a fixed output row; reg index walks N in runs of 4
//   -> packed 8B epilogue stores, row address computed once per mt.
// 2-phase double-buffered pipeline: stage tile k+1 into buf^1 BEFORE
// ds_read+MFMA of buf; single vmcnt(0)-drain barrier per K-step.
// LDS k-chunk XOR-swizzle (chunk ^= row&3) applied on global addr at staging.
// XCD swizzle: lin%8 -> XCD, contiguous M-chunk per XCD for A-tile L2 reuse.
// MODE 0: QKV (epi: +q/v bias, scatter to [b_][h][n][d] bf16)
// MODE 1: proj (epi: +proj_b, bf16 scatter to original token order)
// MODE 2: fc1  (epi: +fc1_b, exact GELU, bf16 ld=HIDN)
// MODE 3: fc2  (epi: +fc2_b, bf16 ld=CCH)
template<int MODE, int NBN>
__global__ __launch_bounds__(256, 2) void gemm256_k(
    const u16* __restrict__ A, const u16* __restrict__ Bw,
    const float* __restrict__ bias,
    const float* __restrict__ qbias, const float* __restrict__ vbias,
    u16* __restrict__ o0, u16* __restrict__ o1, u16* __restrict__ o2,
    int K, int mchunk)
{
  // buf layout: [2][ A:256*32 u16 (16KB) | B:128*32 u16 (8KB) ]  = 48KB total
  __shared__ __align__(16) u16 smem[2 * 12288];
  const int t = threadIdx.x;
  const int lin = blockIdx.x;
  const int xcd = lin & 7;
  const int j = lin >> 3;
  const int m0 = (xcd * mchunk + j / NBN) * 256;
  const int n0 = (j % NBN) * 128;
  const int lane = t & 63;
  const int wv = t >> 6;
  const int wm = (wv & 1) * 128;
  const int wn = (wv >> 1) * 64;
  const int l31 = lane & 31;
  const int khalf = lane >> 5;   // 0/1
  const int sw = lane & 3;       // row&3 for fragment rows

  // staging pointers: LDS chunk c = i*256 + t; row = c>>2, lds k-chunk = c&3,
  // global k-chunk = (c&3) ^ (row&3); row&3 = (t>>2)&3 for all i.
  const int swcol = (((t & 3) ^ ((t >> 2) & 3)) * 8);
  const u16* aP[4]; int aL[4];
  #pragma unroll
  for (int i = 0; i < 4; i++) {
    aP[i] = A + (size_t)(m0 + i * 64 + (t >> 2)) * K + swcol;
    aL[i] = i * 4096 + wv * 1024;
  }
  const u16* bP[2]; int bL[2];
  #pragma unroll
  for (int i = 0; i < 2; i++) {
    bP[i] = Bw + (size_t)(n0 + i * 64 + (t >> 2)) * K + swcol;
    bL[i] = 16384 + i * 4096 + wv * 1024;
  }

  f32x16 acc[4][2] = {};

  // prologue: stage first k-tile into buf 0
  {
    char* base = (char*)smem;
    #pragma unroll
    for (int i = 0; i < 4; i++) gload16(aP[i], base + aL[i]);
    #pragma unroll
    for (int i = 0; i < 2; i++) gload16(bP[i], base + bL[i]);
  }
  __syncthreads();

  int cur = 0;
  for (int k0 = 0; k0 < K; k0 += 32) {
    // prefetch next k-tile into the other buffer (async, in flight over MFMAs)
    if (k0 + 32 < K) {
      char* base = (char*)smem + (cur ^ 1) * 24576;
      #pragma unroll
      for (int i = 0; i < 4; i++) gload16(aP[i] + k0 + 32, base + aL[i]);
      #pragma unroll
      for (int i = 0; i < 2; i++) gload16(bP[i] + k0 + 32, base + bL[i]);
    }
    const u16* Ab = (const u16*)((const char*)smem + cur * 24576);
    const u16* Bb = Ab + 8192;
    #pragma unroll
    for (int ks = 0; ks < 2; ks++) {
      const int kc = (ks * 2 + khalf) ^ sw;   // swizzled k-chunk
      bf16x8 af[4], bf[2];
      #pragma unroll
      for (int mt = 0; mt < 4; mt++)
        af[mt] = *(const bf16x8*)&Ab[(wm + mt * 32 + l31) * 32 + kc * 8];
      #pragma unroll
      for (int nt = 0; nt < 2; nt++)
        bf[nt] = *(const bf16x8*)&Bb[(wn + nt * 32 + l31) * 32 + kc * 8];
      #pragma unroll
      for (int mt = 0; mt < 4; mt++)
        #pragma unroll
        for (int nt = 0; nt < 2; nt++)
          acc[mt][nt] = __builtin_amdgcn_mfma_f32_32x32x16_bf16(bf[nt], af[mt], acc[mt][nt], 0, 0, 0);
    }
    __syncthreads();   // drains vmcnt(0): next buffer complete; reads of cur done
    cur ^= 1;
  }

  // epilogue: acc holds C^T tiles.
  //   out row  = m0 + wm + mt*32 + l31            (fixed per lane)
  //   out col  = n0 + wn + nt*32 + 8*g + 4*khalf + jj   (r = g*4 + jj)
  // -> 4 contiguous channels per reg-group: packed 8B stores, float4 bias.
  const int part = n0 >> 9;   // MODE 0 only (tile never spans q/k/v parts)
  u16* qkvdst = (MODE == 0) ? (part == 0 ? o0 : (part == 1 ? o1 : o2)) : o0;
  #pragma unroll
  for (int mt = 0; mt < 4; mt++) {
    const int grow = m0 + wm + mt * 32 + l31;
    size_t rowbase;
    if (MODE == 0) {
      int b_ = grow >> 6, n = grow & 63;
      rowbase = ((size_t)b_ * HEADS) * (NTOK * DDIM) + (size_t)n * DDIM;
    } else if (MODE == 1) {
      rowbase = (size_t)win2orig(grow >> 6, grow & 63) * CCH;
    } else if (MODE == 2) {
      rowbase = (size_t)grow * HIDN;
    } else {
      rowbase = (size_t)grow * CCH;
    }
    #pragma unroll
    for (int nt = 0; nt < 2; nt++)
      #pragma unroll
      for (int g = 0; g < 4; g++) {
        const int nb = n0 + wn + nt * 32 + 8 * g + 4 * khalf;  // 4-aligned channel base
        float v0 = acc[mt][nt][g * 4 + 0];
        float v1 = acc[mt][nt][g * 4 + 1];
        float v2 = acc[mt][nt][g * 4 + 2];
        float v3 = acc[mt][nt][g * 4 + 3];
        union { u16 o[4]; uint2 u; } pk;
        if (MODE == 0) {
          const int cc = nb & 511;
          if (part == 0) {
            float4 b4 = *(const float4*)(qbias + cc);
            v0 += b4.x; v1 += b4.y; v2 += b4.z; v3 += b4.w;
          } else if (part == 2) {
            float4 b4 = *(const float4*)(vbias + cc);
            v0 += b4.x; v1 += b4.y; v2 += b4.z; v3 += b4.w;
          }
          const int hh = cc >> 5, dd = cc & 31;
          pk.o[0] = f2bf(v0); pk.o[1] = f2bf(v1); pk.o[2] = f2bf(v2); pk.o[3] = f2bf(v3);
          *(uint2*)(qkvdst + rowbase + (size_t)hh * (NTOK * DDIM) + dd) = pk.u;
        } else {
          float4 b4 = *(const float4*)(bias + nb);
          v0 += b4.x; v1 += b4.y; v2 += b4.z; v3 += b4.w;
          if (MODE == 2) {
            v0 = 0.5f * v0 * (1.0f + erff(v0 * 0.70710678118654752f));
            v1 = 0.5f * v1 * (1.0f + erff(v1 * 0.70710678118654752f));
            v2 = 0.5f * v2 * (1.0f + erff(v2 * 0.70710678118654752f));
            v3 = 0.5f * v3 * (1.0f + erff(v3 * 0.70710678118654752f));
          }
          pk.o[0] = f2bf(v0); pk.o[1] = f2bf(v1); pk.o[2] = f2bf(v2); pk.o[3] = f2bf(v3);
          *(uint2*)(o0 + rowbase + nb) = pk.u;
        }
      }
  }
}

// ---------------- attention: one wave per (window, head), in-register softmax ----------------
__global__ __launch_bounds__(64) void attn_k(
    const u16* __restrict__ qb, const u16* __restrict__ kb, const u16* __restrict__ vb,
    const float* __restrict__ bias16, const float* __restrict__ scale,
    const float* __restrict__ amask, u16* __restrict__ attn_out)
{
  __shared__ u16 Pmat[64][72];   // bf16 P (unnormalized), 144B rows (16B-aligned)
  __shared__ u16 vT[32][72];     // V transposed [d][tok]

  int bh = blockIdx.x;
  int b_ = bh >> 4, h = bh & 15;
  int wi = b_ & 63;
  int lane = threadIdx.x;
  int l15 = lane & 15, quad = lane >> 4;
  const u16* qs = qb + (size_t)bh * (NTOK * DDIM);
  const u16* ks = kb + (size_t)bh * (NTOK * DDIM);
  const u16* vs = vb + (size_t)bh * (NTOK * DDIM);

  bf16x8 qf[4], kf[4];
  #pragma unroll
  for (int mt = 0; mt < 4; mt++) {
    qf[mt] = *(const bf16x8*)(qs + (mt * 16 + l15) * DDIM + quad * 8);
    kf[mt] = *(const bf16x8*)(ks + (mt * 16 + l15) * DDIM + quad * 8);
  }
  // fused cosine normalization: lanes {l15, +16, +32, +48} share a row
  #pragma unroll
  for (int mt = 0; mt < 4; mt++) {
    float sq = 0.f, sk = 0.f;
    #pragma unroll
    for (int jj = 0; jj < 8; jj++) {
      float a = bf2f((u16)qf[mt][jj]); sq += a * a;
      float b = bf2f((u16)kf[mt][jj]); sk += b * b;
    }
    sq += __shfl_xor(sq, 16); sq += __shfl_xor(sq, 32);
    sk += __shfl_xor(sk, 16); sk += __shfl_xor(sk, 32);
    float iq = 1.f / fmaxf(sqrtf(sq), 1e-12f);
    float ik = 1.f / fmaxf(sqrtf(sk), 1e-12f);
    #pragma unroll
    for (int jj = 0; jj < 8; jj++) {
      qf[mt][jj] = (short)f2bf(bf2f((u16)qf[mt][jj]) * iq);
      kf[mt][jj] = (short)f2bf(bf2f((u16)kf[mt][jj]) * ik);
    }
  }
  // S = qn @ kn^T (in registers)
  f32x4 s[4][4];
  #pragma unroll
  for (int mt = 0; mt < 4; mt++)
    #pragma unroll
    for (int nt = 0; nt < 4; nt++) {
      f32x4 c = {0.f, 0.f, 0.f, 0.f};
      s[mt][nt] = __builtin_amdgcn_mfma_f32_16x16x32_bf16(qf[mt], kf[nt], c, 0, 0, 0);
    }
  // stage V^T
  #pragma unroll
  for (int d8 = 0; d8 < 4; d8++) {
    bf16x8 vv = *(const bf16x8*)(vs + lane * DDIM + d8 * 8);
    #pragma unroll
    for (int jj = 0; jj < 8; jj++) vT[d8 * 8 + jj][lane] = (u16)vv[jj];
  }

  // in-register softmax: row = mt*16+quad*4+i (16 lanes/row across l15)
  float sc = scale[h];
  float rinv[4][4];
  const float* bbase = bias16 + (size_t)h * 4096;
  const float* mbase = amask + (size_t)wi * 4096;
  #pragma unroll
  for (int mt = 0; mt < 4; mt++) {
    #pragma unroll
    for (int i = 0; i < 4; i++) {
      int row = mt * 16 + quad * 4 + i;
      const float* bro = bbase + row * 64;
      const float* mro = mbase + row * 64;
      float p[4];
      float mx = -1e30f;
      #pragma unroll
      for (int nt = 0; nt < 4; nt++) {
        int col = nt * 16 + l15;
        float vv = s[mt][nt][i] * sc + bro[col] + mro[col];
        p[nt] = vv;
        mx = fmaxf(mx, vv);
      }
      mx = fmaxf(mx, __shfl_xor(mx, 1));
      mx = fmaxf(mx, __shfl_xor(mx, 2));
      mx = fmaxf(mx, __shfl_xor(mx, 4));
      mx = fmaxf(mx, __shfl_xor(mx, 8));
      float sum = 0.f;
      #pragma unroll
      for (int nt = 0; nt < 4; nt++) {
        float e = __expf(p[nt] - mx);
        p[nt] = e;
        sum += e;
      }
      sum += __shfl_xor(sum, 1);
      sum += __shfl_xor(sum, 2);
      sum += __shfl_xor(sum, 4);
      sum += __shfl_xor(sum, 8);
      rinv[mt][i] = 1.f / sum;
      #pragma unroll
      for (int nt = 0; nt < 4; nt++)
        Pmat[row][nt * 16 + l15] = f2bf(p[nt]);
    }
  }
  __syncthreads();

  // O = P @ V (1/sum folded into epilogue)
  f32x4 oacc[4][2] = {};
  #pragma unroll
  for (int ks2 = 0; ks2 < 2; ks2++) {
    bf16x8 pf[4], vf[2];
    #pragma unroll
    for (int mt = 0; mt < 4; mt++)
      pf[mt] = *(const bf16x8*)&Pmat[mt * 16 + l15][ks2 * 32 + quad * 8];
    #pragma unroll
    for (int nt = 0; nt < 2; nt++)
      vf[nt] = *(const bf16x8*)&vT[nt * 16 + l15][ks2 * 32 + quad * 8];
    #pragma unroll
    for (int mt = 0; mt < 4; mt++)
      #pragma unroll
      for (int nt = 0; nt < 2; nt++)
        oacc[mt][nt] = __builtin_amdgcn_mfma_f32_16x16x32_bf16(pf[mt], vf[nt], oacc[mt][nt], 0, 0, 0);
  }
  #pragma unroll
  for (int mt = 0; mt < 4; mt++)
    #pragma unroll
    for (int nt = 0; nt < 2; nt++)
      #pragma unroll
      for (int i = 0; i < 4; i++) {
        int n = mt * 16 + quad * 4 + i;
        int d = nt * 16 + l15;
        float val = oacc[mt][nt][i] * rinv[mt][i];
        attn_out[(size_t)(b_ * 64 + n) * CCH + h * DDIM + d] = f2bf(val);
      }
}

// ---------------- LayerNorm + residual kernels (one wave per row) ----------------
__global__ __launch_bounds__(256) void ln_res_k(
    const float* __restrict__ xin, const u16* __restrict__ pin,
    const float* __restrict__ gam, const float* __restrict__ bet,
    float* __restrict__ x1f, u16* __restrict__ x1b)
{
  int row = blockIdx.x * 4 + (threadIdx.x >> 6);
  int lane = threadIdx.x & 63;
  size_t base = (size_t)row * CCH + lane * 8;
  uint4 u = *(const uint4*)(pin + base);
  unsigned w[4] = {u.x, u.y, u.z, u.w};
  float pv[8];
  #pragma unroll
  for (int j = 0; j < 4; j++) {
    pv[j * 2] = bf2f(w[j] & 0xffffu);
    pv[j * 2 + 1] = bf2f(w[j] >> 16);
  }
  const float* xr = xin + base;
  float s = 0.f, sq = 0.f;
  #pragma unroll
  for (int j = 0; j < 8; j++) { s += pv[j]; sq += pv[j] * pv[j]; }
  #pragma unroll
  for (int o = 32; o > 0; o >>= 1) { s += __shfl_xor(s, o, 64); sq += __shfl_xor(sq, o, 64); }
  float mean = s * (1.0f / 512.0f);
  float var = sq * (1.0f / 512.0f) - mean * mean;
  float rstd = rsqrtf(var + 1e-5f);
  #pragma unroll
  for (int j = 0; j < 8; j++) {
    int c = lane * 8 + j;
    float val = xr[j] + (pv[j] - mean) * rstd * gam[c] + bet[c];
    x1f[base + j] = val;
    x1b[base + j] = f2bf(val);
  }
}

__global__ __launch_bounds__(256) void ln_fin_k(
    const u16* __restrict__ mlp, const float* __restrict__ gam,
    const float* __restrict__ bet, float* __restrict__ io)
{
  int row = blockIdx.x * 4 + (threadIdx.x >> 6);
  int lane = threadIdx.x & 63;
  size_t base = (size_t)row * CCH + lane * 8;
  uint4 u = *(const uint4*)(mlp + base);
  unsigned w[4] = {u.x, u.y, u.z, u.w};
  float pv[8];
  #pragma unroll
  for (int j = 0; j < 4; j++) {
    pv[j * 2] = bf2f(w[j] & 0xffffu);
    pv[j * 2 + 1] = bf2f(w[j] >> 16);
  }
  float s = 0.f, sq = 0.f;
  #pragma unroll
  for (int j = 0; j < 8; j++) { s += pv[j]; sq += pv[j] * pv[j]; }
  #pragma unroll
  for (int o = 32; o > 0; o >>= 1) { s += __shfl_xor(s, o, 64); sq += __shfl_xor(sq, o, 64); }
  float mean = s * (1.0f / 512.0f);
  float var = sq * (1.0f / 512.0f) - mean * mean;
  float rstd = rsqrtf(var + 1e-5f);
  #pragma unroll
  for (int j = 0; j < 8; j++) {
    int c = lane * 8 + j;
    io[base + j] = io[base + j] + (pv[j] - mean) * rstd * gam[c] + bet[c];
  }
}

// ---------------- launcher ----------------
#define OFF_Q     ((size_t)0)
#define OFF_K     ((size_t)67108864)
#define OFF_V     ((size_t)134217728)
#define OFF_ATTN  ((size_t)201326592)
#define OFF_X1B   ((size_t)268435456)
#define OFF_WQKV  ((size_t)335544320)
#define OFF_WPROJ ((size_t)337117184)
#define OFF_WFC1  ((size_t)337641472)
#define OFF_WFC2  ((size_t)339738624)
#define OFF_T2    ((size_t)341835776)
#define OFF_B16   ((size_t)341852160)
#define OFF_SC    ((size_t)342114304)

extern "C" void kernel_launch(void* const* d_in, const int* in_sizes, int n_in,
                              void* d_out, int out_size, void* d_ws, size_t ws_size,
                              hipStream_t stream) {
  const float* x        = (const float*)d_in[0];
  const float* qkv_w    = (const float*)d_in[1];
  const float* q_bias   = (const float*)d_in[2];
  const float* v_bias   = (const float*)d_in[3];
  const float* lscale   = (const float*)d_in[4];
  const float* cpb_w1   = (const float*)d_in[5];
  const float* cpb_b1   = (const float*)d_in[6];
  const float* cpb_w2   = (const float*)d_in[7];
  const float* proj_w   = (const float*)d_in[8];
  const float* proj_b   = (const float*)d_in[9];
  const float* n1g      = (const float*)d_in[10];
  const float* n1b      = (const float*)d_in[11];
  const float* n2g      = (const float*)d_in[12];
  const float* n2b      = (const float*)d_in[13];
  const float* fc1_w    = (const float*)d_in[14];
  const float* fc1_b    = (const float*)d_in[15];
  const float* fc2_w    = (const float*)d_in[16];
  const float* fc2_b    = (const float*)d_in[17];
  const float* ctab     = (const float*)d_in[18];
  const float* amask    = (const float*)d_in[19];
  const int*   rpi      = (const int*)d_in[20];

  char* ws = (char*)d_ws;
  float* outp = (float*)d_out;

  u16*   q_buf    = (u16*)(ws + OFF_Q);
  u16*   k_buf    = (u16*)(ws + OFF_K);
  u16*   v_buf    = (u16*)(ws + OFF_V);
  u16*   proj_out = (u16*)(ws + OFF_Q);     // reuse R0 (bf16 now)
  u16*   hid      = (u16*)(ws + OFF_Q);     // reuse R0 (half-batch)
  u16*   xw       = (u16*)(ws + OFF_ATTN);  // R1 (dead after QKV gemm)
  u16*   attn_out = (u16*)(ws + OFF_ATTN);
  u16*   mlp_out  = (u16*)(ws + OFF_ATTN);
  u16*   x1b      = (u16*)(ws + OFF_X1B);
  u16*   wqkv     = (u16*)(ws + OFF_WQKV);
  u16*   wproj    = (u16*)(ws + OFF_WPROJ);
  u16*   wfc1     = (u16*)(ws + OFF_WFC1);
  u16*   wfc2     = (u16*)(ws + OFF_WFC2);
  float* t2       = (float*)(ws + OFF_T2);
  float* b16      = (float*)(ws + OFF_B16);
  float* scbuf    = (float*)(ws + OFF_SC);

  cvt_k<<<(1536 * 512 + 255) / 256, 256, 0, stream>>>(qkv_w, wqkv, 1536 * 512);
  cvt_k<<<(512 * 512 + 255) / 256, 256, 0, stream>>>(proj_w, wproj, 512 * 512);
  cvt_k<<<(2048 * 512 + 255) / 256, 256, 0, stream>>>(fc1_w, wfc1, 2048 * 512);
  cvt_k<<<(512 * 2048 + 255) / 256, 256, 0, stream>>>(fc2_w, wfc2, 512 * 2048);
  cpb_k<<<15, 256, 0, stream>>>(ctab, cpb_w1, cpb_b1, cpb_w2, t2);
  bias_k<<<256, 256, 0, stream>>>(t2, rpi, b16);
  scale_k<<<1, 64, 0, stream>>>(lscale, scbuf);

  // x -> xw (bf16, shifted-window order)
  xw_k<<<MTOT * 64 / 256, 256, 0, stream>>>(x, xw);
  // QKV: M=65536 (256 m-tiles), N=1536 (12 n-tiles)
  gemm256_k<0, 12><<<256 * 12, 256, 0, stream>>>(
      xw, wqkv, nullptr, q_bias, v_bias, q_buf, k_buf, v_buf, 512, 32);
  // attention (fused cosine norm, in-register softmax)
  attn_k<<<BWIN * HEADS, 64, 0, stream>>>(q_buf, k_buf, v_buf, b16, scbuf, amask, attn_out);
  // proj: N=512 (4 n-tiles), bf16 out, window-reverse fused
  gemm256_k<1, 4><<<256 * 4, 256, 0, stream>>>(
      attn_out, wproj, proj_b, nullptr, nullptr, proj_out, nullptr, nullptr, 512, 32);
  // x1 = x + LN1(proj_out)
  ln_res_k<<<MTOT / 4, 256, 0, stream>>>(x, proj_out, n1g, n1b, outp, x1b);
  // MLP in two row-halves
  for (int half = 0; half < 2; half++) {
    const u16* a1 = x1b + (size_t)half * (MTOT / 2) * CCH;
    u16* m1 = mlp_out + (size_t)half * (MTOT / 2) * CCH;
    gemm256_k<2, 16><<<128 * 16, 256, 0, stream>>>(
        a1, wfc1, fc1_b, nullptr, nullptr, hid, nullptr, nullptr, 512, 16);
    gemm256_k<3, 4><<<128 * 4, 256, 0, stream>>>(
        hid, wfc2, fc2_b, nullptr, nullptr, m1, nullptr, nullptr, 2048, 16);
  }
  // out = x1 + LN2(mlp)
  ln_fin_k<<<MTOT / 4, 256, 0, stream>>>(mlp_out, n2g, n2b, outp);
}

// Round 2
// 1150.179 us; speedup vs baseline: 1.1709x; 1.1029x over previous
//
#include <hip/hip_runtime.h>
#include <hip/hip_bf16.h>
#include <math.h>

// ---- problem constants ----
#define BB     16
#define HH     64
#define WWID   64
#define CCH    512
#define HEADS  16
#define NTOK   64
#define DDIM   32
#define NWIN   64
#define LL     (HH*WWID)       // 4096
#define MTOT   (BB*LL)         // 65536 rows
#define BWIN   (BB*NWIN)       // 1024 windows
#define HIDN   2048
#define SHIFT_ 4

typedef unsigned short u16;
using bf16x8 = __attribute__((ext_vector_type(8))) short;   // 8 bf16 (4 VGPRs)
using f32x4  = __attribute__((ext_vector_type(4))) float;
using f32x16 = __attribute__((ext_vector_type(16))) float;

__device__ __forceinline__ u16 f2bf(float f) {
  union { float f; unsigned u; } v; v.f = f;
  unsigned r = v.u + 0x7fffu + ((v.u >> 16) & 1u);   // RNE
  return (u16)(r >> 16);
}
__device__ __forceinline__ float bf2f(unsigned h) {
  union { unsigned u; float f; } v; v.u = h << 16;
  return v.f;
}

__device__ __forceinline__ void gload16(const void* g, void* l) {
  __builtin_amdgcn_global_load_lds((const __attribute__((address_space(1))) void*)g,
                                   (__attribute__((address_space(3))) void*)l, 16, 0, 0);
}

// shifted-window mapping: windowed token (b_, n) -> original row index in x
__device__ __forceinline__ int win2orig(int b_, int n) {
  int b = b_ >> 6, wi = b_ & 63;
  int hs = (wi >> 3) * 8 + (n >> 3);
  int ws = (wi & 7) * 8 + (n & 7);
  int hq = (hs + SHIFT_) & 63;
  int wq = (ws + SHIFT_) & 63;
  return b * LL + hq * WWID + wq;
}

// ---------------- tiny setup kernels ----------------
__global__ void cvt_k(const float* __restrict__ s, u16* __restrict__ d, int n) {
  int i = blockIdx.x * 256 + threadIdx.x;
  if (i < n) d[i] = f2bf(s[i]);
}

__global__ void cpb_k(const float* __restrict__ ct, const float* __restrict__ w1,
                      const float* __restrict__ b1, const float* __restrict__ w2,
                      float* __restrict__ t2) {
  int t = blockIdx.x * 256 + threadIdx.x;
  if (t >= 225 * 16) return;
  int rr = t >> 4, h = t & 15;
  float c0 = ct[rr * 2], c1 = ct[rr * 2 + 1];
  float acc = 0.f;
  for (int j = 0; j < 512; j++) {
    float hv = fmaxf(w1[j * 2] * c0 + w1[j * 2 + 1] * c1 + b1[j], 0.f);
    acc += hv * w2[h * 512 + j];
  }
  t2[t] = acc;
}

__global__ void bias_k(const float* __restrict__ t2, const int* __restrict__ rpi,
                       float* __restrict__ b16) {
  int t = blockIdx.x * 256 + threadIdx.x;   // h*4096 + n*64 + m
  int nm = t & 4095;
  int h = t >> 12;
  float v = t2[rpi[nm] * 16 + h];
  b16[t] = 16.0f / (1.0f + __expf(-v));
}

__global__ void scale_k(const float* __restrict__ ls, float* __restrict__ sc) {
  int t = threadIdx.x;
  if (t < HEADS) sc[t] = __expf(fminf(ls[t], 4.6051701859880914f)); // ln(100)
}

// x (fp32) -> xw (bf16) in shifted-window token order [b_*64+n][512]
__global__ __launch_bounds__(256) void xw_k(const float* __restrict__ x, u16* __restrict__ xw) {
  int t = blockIdx.x * 256 + threadIdx.x;
  int row = t >> 6;
  int col = (t & 63) * 8;
  const float* src = x + (size_t)win2orig(row >> 6, row & 63) * CCH + col;
  float4 a = *(const float4*)src;
  float4 b = *(const float4*)(src + 4);
  u16 o[8] = {f2bf(a.x), f2bf(a.y), f2bf(a.z), f2bf(a.w),
              f2bf(b.x), f2bf(b.y), f2bf(b.z), f2bf(b.w)};
  *(uint4*)(xw + (size_t)row * CCH + col) = *(const uint4*)o;
}

// ---------------- MFMA GEMM, 256x128 block tile, 32x32x16 MFMA ----------------
// A bf16 [M][K], B bf16 [N][K] -> C = A @ B^T.  4 waves, wave tile 128x64.
// mfma(b,a): acc holds C^T; lane owns a fixed output row, regs walk N.
// Epilogue: v_permlane32_swap_b32 reassembles the khalf-interleaved 4-channel
//   groups into 8 contiguous channels/lane -> 16B uint4 stores; lane pair
//   (l31, l31+32) covers adjacent 16B -> full 32B sectors per instruction
//   (fixes partial-sector write amplification seen in rocprof WRITE_SIZE).
// Main loop: depth-2 pipeline, 3 LDS buffers, raw s_barrier + counted
//   s_waitcnt vmcnt(6) (6 gload_lds per tile per thread; never drains to 0
//   in steady state) -> each tile's loads get ~2 compute phases to land.
// LDS k-chunk XOR-swizzle (chunk ^= row&3) applied on global addr at staging.
// XCD swizzle: lin%8 -> XCD, contiguous M-chunk per XCD for A-tile L2 reuse.
// MODE 0: QKV (epi: +q/v bias, scatter to [b_][h][n][d] bf16)
// MODE 1: proj (epi: +proj_b, bf16 scatter to original token order)
// MODE 2: fc1  (epi: +fc1_b, exact GELU, bf16 ld=HIDN)
// MODE 3: fc2  (epi: +fc2_b, bf16 ld=CCH)
template<int MODE, int NBN>
__global__ __launch_bounds__(256, 2) void gemm256_k(
    const u16* __restrict__ A, const u16* __restrict__ Bw,
    const float* __restrict__ bias,
    const float* __restrict__ qbias, const float* __restrict__ vbias,
    u16* __restrict__ o0, u16* __restrict__ o1, u16* __restrict__ o2,
    int K, int mchunk)
{
  // buf layout: [3][ A:256*32 u16 (16KB) | B:128*32 u16 (8KB) ]  = 72KB total
  __shared__ __align__(16) u16 smem[3 * 12288];
  const int t = threadIdx.x;
  const int lin = blockIdx.x;
  const int xcd = lin & 7;
  const int j = lin >> 3;
  const int m0 = (xcd * mchunk + j / NBN) * 256;
  const int n0 = (j % NBN) * 128;
  const int lane = t & 63;
  const int wv = t >> 6;
  const int wm = (wv & 1) * 128;
  const int wn = (wv >> 1) * 64;
  const int l31 = lane & 31;
  const int khalf = lane >> 5;   // 0/1
  const int sw = lane & 3;       // row&3 for fragment rows

  // staging pointers: LDS chunk c = i*256 + t; row = c>>2, lds k-chunk = c&3,
  // global k-chunk = (c&3) ^ (row&3); row&3 = (t>>2)&3 for all i.
  const int swcol = (((t & 3) ^ ((t >> 2) & 3)) * 8);
  const u16* aP[4]; int aL[4];
  #pragma unroll
  for (int i = 0; i < 4; i++) {
    aP[i] = A + (size_t)(m0 + i * 64 + (t >> 2)) * K + swcol;
    aL[i] = i * 4096 + wv * 1024;
  }
  const u16* bP[2]; int bL[2];
  #pragma unroll
  for (int i = 0; i < 2; i++) {
    bP[i] = Bw + (size_t)(n0 + i * 64 + (t >> 2)) * K + swcol;
    bL[i] = 16384 + i * 4096 + wv * 1024;
  }

  f32x16 acc[4][2] = {};

  auto stage = [&](int k0, int bi) {
    char* base = (char*)smem + bi * 24576;
    #pragma unroll
    for (int i = 0; i < 4; i++) gload16(aP[i] + k0, base + aL[i]);
    #pragma unroll
    for (int i = 0; i < 2; i++) gload16(bP[i] + k0, base + bL[i]);
  };

  const int NT = K >> 5;
  // prologue: stage tiles 0 and 1
  stage(0, 0);
  stage(32, 1);

  for (int it = 0; it < NT; ++it) {
    // own tile-it loads complete (oldest); tile it+1 may stay in flight
    if (it + 1 < NT) asm volatile("s_waitcnt vmcnt(6)" ::: "memory");
    else             asm volatile("s_waitcnt vmcnt(0)" ::: "memory");
    __builtin_amdgcn_s_barrier();       // all waves: tile it ready; reads of it-1 done
    asm volatile("" ::: "memory");      // keep ds_reads below the barrier
    if (it + 2 < NT) stage((it + 2) << 5, (it + 2) % 3);

    const u16* Ab = (const u16*)((const char*)smem + (it % 3) * 24576);
    const u16* Bb = Ab + 8192;
    #pragma unroll
    for (int ks = 0; ks < 2; ks++) {
      const int kc = (ks * 2 + khalf) ^ sw;   // swizzled k-chunk
      bf16x8 af[4], bf[2];
      #pragma unroll
      for (int mt = 0; mt < 4; mt++)
        af[mt] = *(const bf16x8*)&Ab[(wm + mt * 32 + l31) * 32 + kc * 8];
      #pragma unroll
      for (int nt = 0; nt < 2; nt++)
        bf[nt] = *(const bf16x8*)&Bb[(wn + nt * 32 + l31) * 32 + kc * 8];
      #pragma unroll
      for (int mt = 0; mt < 4; mt++)
        #pragma unroll
        for (int nt = 0; nt < 2; nt++)
          acc[mt][nt] = __builtin_amdgcn_mfma_f32_32x32x16_bf16(bf[nt], af[mt], acc[mt][nt], 0, 0, 0);
    }
    // next iteration's barrier protects buffer reuse (reads of tile it are
    // consumed by the MFMAs above before any wave passes that barrier)
  }

  // epilogue: acc holds C^T tiles.
  //   row = m0+wm+mt*32+l31 (fixed/lane); own cols = cb + 8g + 4*khalf (+0..3)
  // permlane32_swap(U_g, U_{g+1}): U_g' = {own cols 8g+0..1 | partner 8(g+1)..}
  // -> lane stores 8 contiguous channels; pair covers 32B-aligned sector.
  const int part = n0 >> 9;   // MODE 0 only (tile never spans q/k/v parts)
  u16* qkvdst = (MODE == 0) ? (part == 0 ? o0 : (part == 1 ? o1 : o2)) : o0;
  #pragma unroll
  for (int mt = 0; mt < 4; mt++) {
    const int grow = m0 + wm + mt * 32 + l31;
    size_t rowbase;
    if (MODE == 0) {
      int b_ = grow >> 6, n = grow & 63;
      rowbase = ((size_t)b_ * HEADS) * (NTOK * DDIM) + (size_t)n * DDIM;
    } else if (MODE == 1) {
      rowbase = (size_t)win2orig(grow >> 6, grow & 63) * CCH;
    } else if (MODE == 2) {
      rowbase = (size_t)grow * HIDN;
    } else {
      rowbase = (size_t)grow * CCH;
    }
    #pragma unroll
    for (int nt = 0; nt < 2; nt++) {
      const int cb = n0 + wn + nt * 32;          // 32-aligned channel base
      unsigned U[4], W[4];
      #pragma unroll
      for (int g = 0; g < 4; g++) {
        const int nb = cb + 8 * g + 4 * khalf;
        float v0 = acc[mt][nt][g * 4 + 0];
        float v1 = acc[mt][nt][g * 4 + 1];
        float v2 = acc[mt][nt][g * 4 + 2];
        float v3 = acc[mt][nt][g * 4 + 3];
        if (MODE == 0) {
          const int cc = nb & 511;
          if (part == 0) {
            float4 b4 = *(const float4*)(qbias + cc);
            v0 += b4.x; v1 += b4.y; v2 += b4.z; v3 += b4.w;
          } else if (part == 2) {
            float4 b4 = *(const float4*)(vbias + cc);
            v0 += b4.x; v1 += b4.y; v2 += b4.z; v3 += b4.w;
          }
        } else {
          float4 b4 = *(const float4*)(bias + nb);
          v0 += b4.x; v1 += b4.y; v2 += b4.z; v3 += b4.w;
          if (MODE == 2) {
            v0 = 0.5f * v0 * (1.0f + erff(v0 * 0.70710678118654752f));
            v1 = 0.5f * v1 * (1.0f + erff(v1 * 0.70710678118654752f));
            v2 = 0.5f * v2 * (1.0f + erff(v2 * 0.70710678118654752f));
            v3 = 0.5f * v3 * (1.0f + erff(v3 * 0.70710678118654752f));
          }
        }
        U[g] = (unsigned)f2bf(v0) | ((unsigned)f2bf(v1) << 16);
        W[g] = (unsigned)f2bf(v2) | ((unsigned)f2bf(v3) << 16);
      }
      // A.high <-> B.low swaps: assemble 8 contiguous channels per lane
      asm volatile("v_permlane32_swap_b32 %0, %1" : "+v"(U[0]), "+v"(U[1]));
      asm volatile("v_permlane32_swap_b32 %0, %1" : "+v"(W[0]), "+v"(W[1]));
      asm volatile("v_permlane32_swap_b32 %0, %1" : "+v"(U[2]), "+v"(U[3]));
      asm volatile("v_permlane32_swap_b32 %0, %1" : "+v"(W[2]), "+v"(W[3]));
      uint4 s1 = make_uint4(U[0], W[0], U[1], W[1]);   // cols [cb+8k, cb+8k+8)
      uint4 s2 = make_uint4(U[2], W[2], U[3], W[3]);   // cols [cb+16+8k, +8)
      if (MODE == 0) {
        const int cc1 = (cb & 511) + 8 * khalf;
        const int cc2 = cc1 + 16;
        *(uint4*)(qkvdst + rowbase + (size_t)(cc1 >> 5) * (NTOK * DDIM) + (cc1 & 31)) = s1;
        *(uint4*)(qkvdst + rowbase + (size_t)(cc2 >> 5) * (NTOK * DDIM) + (cc2 & 31)) = s2;
      } else {
        *(uint4*)(o0 + rowbase + cb + 8 * khalf) = s1;
        *(uint4*)(o0 + rowbase + cb + 16 + 8 * khalf) = s2;
      }
    }
  }
}

// ---------------- attention: one wave per (window, head), in-register softmax ----------------
__global__ __launch_bounds__(64) void attn_k(
    const u16* __restrict__ qb, const u16* __restrict__ kb, const u16* __restrict__ vb,
    const float* __restrict__ bias16, const float* __restrict__ scale,
    const float* __restrict__ amask, u16* __restrict__ attn_out)
{
  __shared__ u16 Pmat[64][72];   // bf16 P (unnormalized), 144B rows (16B-aligned)
  __shared__ u16 vT[32][72];     // V transposed [d][tok]

  int bh = blockIdx.x;
  int b_ = bh >> 4, h = bh & 15;
  int wi = b_ & 63;
  int lane = threadIdx.x;
  int l15 = lane & 15, quad = lane >> 4;
  const u16* qs = qb + (size_t)bh * (NTOK * DDIM);
  const u16* ks = kb + (size_t)bh * (NTOK * DDIM);
  const u16* vs = vb + (size_t)bh * (NTOK * DDIM);

  bf16x8 qf[4], kf[4];
  #pragma unroll
  for (int mt = 0; mt < 4; mt++) {
    qf[mt] = *(const bf16x8*)(qs + (mt * 16 + l15) * DDIM + quad * 8);
    kf[mt] = *(const bf16x8*)(ks + (mt * 16 + l15) * DDIM + quad * 8);
  }
  // fused cosine normalization: lanes {l15, +16, +32, +48} share a row
  #pragma unroll
  for (int mt = 0; mt < 4; mt++) {
    float sq = 0.f, sk = 0.f;
    #pragma unroll
    for (int jj = 0; jj < 8; jj++) {
      float a = bf2f((u16)qf[mt][jj]); sq += a * a;
      float b = bf2f((u16)kf[mt][jj]); sk += b * b;
    }
    sq += __shfl_xor(sq, 16); sq += __shfl_xor(sq, 32);
    sk += __shfl_xor(sk, 16); sk += __shfl_xor(sk, 32);
    float iq = 1.f / fmaxf(sqrtf(sq), 1e-12f);
    float ik = 1.f / fmaxf(sqrtf(sk), 1e-12f);
    #pragma unroll
    for (int jj = 0; jj < 8; jj++) {
      qf[mt][jj] = (short)f2bf(bf2f((u16)qf[mt][jj]) * iq);
      kf[mt][jj] = (short)f2bf(bf2f((u16)kf[mt][jj]) * ik);
    }
  }
  // S = qn @ kn^T (in registers)
  f32x4 s[4][4];
  #pragma unroll
  for (int mt = 0; mt < 4; mt++)
    #pragma unroll
    for (int nt = 0; nt < 4; nt++) {
      f32x4 c = {0.f, 0.f, 0.f, 0.f};
      s[mt][nt] = __builtin_amdgcn_mfma_f32_16x16x32_bf16(qf[mt], kf[nt], c, 0, 0, 0);
    }
  // stage V^T
  #pragma unroll
  for (int d8 = 0; d8 < 4; d8++) {
    bf16x8 vv = *(const bf16x8*)(vs + lane * DDIM + d8 * 8);
    #pragma unroll
    for (int jj = 0; jj < 8; jj++) vT[d8 * 8 + jj][lane] = (u16)vv[jj];
  }

  // in-register softmax: row = mt*16+quad*4+i (16 lanes/row across l15)
  float sc = scale[h];
  float rinv[4][4];
  const float* bbase = bias16 + (size_t)h * 4096;
  const float* mbase = amask + (size_t)wi * 4096;
  #pragma unroll
  for (int mt = 0; mt < 4; mt++) {
    #pragma unroll
    for (int i = 0; i < 4; i++) {
      int row = mt * 16 + quad * 4 + i;
      const float* bro = bbase + row * 64;
      const float* mro = mbase + row * 64;
      float p[4];
      float mx = -1e30f;
      #pragma unroll
      for (int nt = 0; nt < 4; nt++) {
        int col = nt * 16 + l15;
        float vv = s[mt][nt][i] * sc + bro[col] + mro[col];
        p[nt] = vv;
        mx = fmaxf(mx, vv);
      }
      mx = fmaxf(mx, __shfl_xor(mx, 1));
      mx = fmaxf(mx, __shfl_xor(mx, 2));
      mx = fmaxf(mx, __shfl_xor(mx, 4));
      mx = fmaxf(mx, __shfl_xor(mx, 8));
      float sum = 0.f;
      #pragma unroll
      for (int nt = 0; nt < 4; nt++) {
        float e = __expf(p[nt] - mx);
        p[nt] = e;
        sum += e;
      }
      sum += __shfl_xor(sum, 1);
      sum += __shfl_xor(sum, 2);
      sum += __shfl_xor(sum, 4);
      sum += __shfl_xor(sum, 8);
      rinv[mt][i] = 1.f / sum;
      #pragma unroll
      for (int nt = 0; nt < 4; nt++)
        Pmat[row][nt * 16 + l15] = f2bf(p[nt]);
    }
  }
  __syncthreads();

  // O = P @ V (1/sum folded into epilogue)
  f32x4 oacc[4][2] = {};
  #pragma unroll
  for (int ks2 = 0; ks2 < 2; ks2++) {
    bf16x8 pf[4], vf[2];
    #pragma unroll
    for (int mt = 0; mt < 4; mt++)
      pf[mt] = *(const bf16x8*)&Pmat[mt * 16 + l15][ks2 * 32 + quad * 8];
    #pragma unroll
    for (int nt = 0; nt < 2; nt++)
      vf[nt] = *(const bf16x8*)&vT[nt * 16 + l15][ks2 * 32 + quad * 8];
    #pragma unroll
    for (int mt = 0; mt < 4; mt++)
      #pragma unroll
      for (int nt = 0; nt < 2; nt++)
        oacc[mt][nt] = __builtin_amdgcn_mfma_f32_16x16x32_bf16(pf[mt], vf[nt], oacc[mt][nt], 0, 0, 0);
  }
  #pragma unroll
  for (int mt = 0; mt < 4; mt++)
    #pragma unroll
    for (int nt = 0; nt < 2; nt++)
      #pragma unroll
      for (int i = 0; i < 4; i++) {
        int n = mt * 16 + quad * 4 + i;
        int d = nt * 16 + l15;
        float val = oacc[mt][nt][i] * rinv[mt][i];
        attn_out[(size_t)(b_ * 64 + n) * CCH + h * DDIM + d] = f2bf(val);
      }
}

// ---------------- LayerNorm + residual kernels (one wave per row) ----------------
__global__ __launch_bounds__(256) void ln_res_k(
    const float* __restrict__ xin, const u16* __restrict__ pin,
    const float* __restrict__ gam, const float* __restrict__ bet,
    float* __restrict__ x1f, u16* __restrict__ x1b)
{
  int row = blockIdx.x * 4 + (threadIdx.x >> 6);
  int lane = threadIdx.x & 63;
  size_t base = (size_t)row * CCH + lane * 8;
  uint4 u = *(const uint4*)(pin + base);
  unsigned w[4] = {u.x, u.y, u.z, u.w};
  float pv[8];
  #pragma unroll
  for (int j = 0; j < 4; j++) {
    pv[j * 2] = bf2f(w[j] & 0xffffu);
    pv[j * 2 + 1] = bf2f(w[j] >> 16);
  }
  const float* xr = xin + base;
  float s = 0.f, sq = 0.f;
  #pragma unroll
  for (int j = 0; j < 8; j++) { s += pv[j]; sq += pv[j] * pv[j]; }
  #pragma unroll
  for (int o = 32; o > 0; o >>= 1) { s += __shfl_xor(s, o, 64); sq += __shfl_xor(sq, o, 64); }
  float mean = s * (1.0f / 512.0f);
  float var = sq * (1.0f / 512.0f) - mean * mean;
  float rstd = rsqrtf(var + 1e-5f);
  #pragma unroll
  for (int j = 0; j < 8; j++) {
    int c = lane * 8 + j;
    float val = xr[j] + (pv[j] - mean) * rstd * gam[c] + bet[c];
    x1f[base + j] = val;
    x1b[base + j] = f2bf(val);
  }
}

__global__ __launch_bounds__(256) void ln_fin_k(
    const u16* __restrict__ mlp, const float* __restrict__ gam,
    const float* __restrict__ bet, float* __restrict__ io)
{
  int row = blockIdx.x * 4 + (threadIdx.x >> 6);
  int lane = threadIdx.x & 63;
  size_t base = (size_t)row * CCH + lane * 8;
  uint4 u = *(const uint4*)(mlp + base);
  unsigned w[4] = {u.x, u.y, u.z, u.w};
  float pv[8];
  #pragma unroll
  for (int j = 0; j < 4; j++) {
    pv[j * 2] = bf2f(w[j] & 0xffffu);
    pv[j * 2 + 1] = bf2f(w[j] >> 16);
  }
  float s = 0.f, sq = 0.f;
  #pragma unroll
  for (int j = 0; j < 8; j++) { s += pv[j]; sq += pv[j] * pv[j]; }
  #pragma unroll
  for (int o = 32; o > 0; o >>= 1) { s += __shfl_xor(s, o, 64); sq += __shfl_xor(sq, o, 64); }
  float mean = s * (1.0f / 512.0f);
  float var = sq * (1.0f / 512.0f) - mean * mean;
  float rstd = rsqrtf(var + 1e-5f);
  #pragma unroll
  for (int j = 0; j < 8; j++) {
    int c = lane * 8 + j;
    io[base + j] = io[base + j] + (pv[j] - mean) * rstd * gam[c] + bet[c];
  }
}

// ---------------- launcher ----------------
#define OFF_Q     ((size_t)0)
#define OFF_K     ((size_t)67108864)
#define OFF_V     ((size_t)134217728)
#define OFF_ATTN  ((size_t)201326592)
#define OFF_X1B   ((size_t)268435456)
#define OFF_WQKV  ((size_t)335544320)
#define OFF_WPROJ ((size_t)337117184)
#define OFF_WFC1  ((size_t)337641472)
#define OFF_WFC2  ((size_t)339738624)
#define OFF_T2    ((size_t)341835776)
#define OFF_B16   ((size_t)341852160)
#define OFF_SC    ((size_t)342114304)

extern "C" void kernel_launch(void* const* d_in, const int* in_sizes, int n_in,
                              void* d_out, int out_size, void* d_ws, size_t ws_size,
                              hipStream_t stream) {
  const float* x        = (const float*)d_in[0];
  const float* qkv_w    = (const float*)d_in[1];
  const float* q_bias   = (const float*)d_in[2];
  const float* v_bias   = (const float*)d_in[3];
  const float* lscale   = (const float*)d_in[4];
  const float* cpb_w1   = (const float*)d_in[5];
  const float* cpb_b1   = (const float*)d_in[6];
  const float* cpb_w2   = (const float*)d_in[7];
  const float* proj_w   = (const float*)d_in[8];
  const float* proj_b   = (const float*)d_in[9];
  const float* n1g      = (const float*)d_in[10];
  const float* n1b      = (const float*)d_in[11];
  const float* n2g      = (const float*)d_in[12];
  const float* n2b      = (const float*)d_in[13];
  const float* fc1_w    = (const float*)d_in[14];
  const float* fc1_b    = (const float*)d_in[15];
  const float* fc2_w    = (const float*)d_in[16];
  const float* fc2_b    = (const float*)d_in[17];
  const float* ctab     = (const float*)d_in[18];
  const float* amask    = (const float*)d_in[19];
  const int*   rpi      = (const int*)d_in[20];

  char* ws = (char*)d_ws;
  float* outp = (float*)d_out;

  u16*   q_buf    = (u16*)(ws + OFF_Q);
  u16*   k_buf    = (u16*)(ws + OFF_K);
  u16*   v_buf    = (u16*)(ws + OFF_V);
  u16*   proj_out = (u16*)(ws + OFF_Q);     // reuse R0 (bf16 now)
  u16*   hid      = (u16*)(ws + OFF_Q);     // reuse R0 (half-batch)
  u16*   xw       = (u16*)(ws + OFF_ATTN);  // R1 (dead after QKV gemm)
  u16*   attn_out = (u16*)(ws + OFF_ATTN);
  u16*   mlp_out  = (u16*)(ws + OFF_ATTN);
  u16*   x1b      = (u16*)(ws + OFF_X1B);
  u16*   wqkv     = (u16*)(ws + OFF_WQKV);
  u16*   wproj    = (u16*)(ws + OFF_WPROJ);
  u16*   wfc1     = (u16*)(ws + OFF_WFC1);
  u16*   wfc2     = (u16*)(ws + OFF_WFC2);
  float* t2       = (float*)(ws + OFF_T2);
  float* b16      = (float*)(ws + OFF_B16);
  float* scbuf    = (float*)(ws + OFF_SC);

  cvt_k<<<(1536 * 512 + 255) / 256, 256, 0, stream>>>(qkv_w, wqkv, 1536 * 512);
  cvt_k<<<(512 * 512 + 255) / 256, 256, 0, stream>>>(proj_w, wproj, 512 * 512);
  cvt_k<<<(2048 * 512 + 255) / 256, 256, 0, stream>>>(fc1_w, wfc1, 2048 * 512);
  cvt_k<<<(512 * 2048 + 255) / 256, 256, 0, stream>>>(fc2_w, wfc2, 512 * 2048);
  cpb_k<<<15, 256, 0, stream>>>(ctab, cpb_w1, cpb_b1, cpb_w2, t2);
  bias_k<<<256, 256, 0, stream>>>(t2, rpi, b16);
  scale_k<<<1, 64, 0, stream>>>(lscale, scbuf);

  // x -> xw (bf16, shifted-window order)
  xw_k<<<MTOT * 64 / 256, 256, 0, stream>>>(x, xw);
  // QKV: M=65536 (256 m-tiles), N=1536 (12 n-tiles)
  gemm256_k<0, 12><<<256 * 12, 256, 0, stream>>>(
      xw, wqkv, nullptr, q_bias, v_bias, q_buf, k_buf, v_buf, 512, 32);
  // attention (fused cosine norm, in-register softmax)
  attn_k<<<BWIN * HEADS, 64, 0, stream>>>(q_buf, k_buf, v_buf, b16, scbuf, amask, attn_out);
  // proj: N=512 (4 n-tiles), bf16 out, window-reverse fused
  gemm256_k<1, 4><<<256 * 4, 256, 0, stream>>>(
      attn_out, wproj, proj_b, nullptr, nullptr, proj_out, nullptr, nullptr, 512, 32);
  // x1 = x + LN1(proj_out)
  ln_res_k<<<MTOT / 4, 256, 0, stream>>>(x, proj_out, n1g, n1b, outp, x1b);
  // MLP in two row-halves
  for (int half = 0; half < 2; half++) {
    const u16* a1 = x1b + (size_t)half * (MTOT / 2) * CCH;
    u16* m1 = mlp_out + (size_t)half * (MTOT / 2) * CCH;
    gemm256_k<2, 16><<<128 * 16, 256, 0, stream>>>(
        a1, wfc1, fc1_b, nullptr, nullptr, hid, nullptr, nullptr, 512, 16);
    gemm256_k<3, 4><<<128 * 4, 256, 0, stream>>>(
        hid, wfc2, fc2_b, nullptr, nullptr, m1, nullptr, nullptr, 2048, 16);
  }
  // out = x1 + LN2(mlp)
  ln_fin_k<<<MTOT / 4, 256, 0, stream>>>(mlp_out, n2g, n2b, outp);
}

// Round 3
// 1052.424 us; speedup vs baseline: 1.2796x; 1.0929x over previous
//
#include <hip/hip_runtime.h>
#include <hip/hip_bf16.h>
#include <math.h>

// ---- problem constants ----
#define BB     16
#define HH     64
#define WWID   64
#define CCH    512
#define HEADS  16
#define NTOK   64
#define DDIM   32
#define NWIN   64
#define LL     (HH*WWID)       // 4096
#define MTOT   (BB*LL)         // 65536 rows
#define BWIN   (BB*NWIN)       // 1024 windows
#define HIDN   2048
#define SHIFT_ 4

typedef unsigned short u16;
using bf16x8 = __attribute__((ext_vector_type(8))) short;   // 8 bf16 (4 VGPRs)
using f32x4  = __attribute__((ext_vector_type(4))) float;
using f32x16 = __attribute__((ext_vector_type(16))) float;

__device__ __forceinline__ u16 f2bf(float f) {
  union { float f; unsigned u; } v; v.f = f;
  unsigned r = v.u + 0x7fffu + ((v.u >> 16) & 1u);   // RNE
  return (u16)(r >> 16);
}
__device__ __forceinline__ float bf2f(unsigned h) {
  union { unsigned u; float f; } v; v.u = h << 16;
  return v.f;
}
// packed f32x2 -> bf16x2 (hardware RNE, 1 instr for 2 elems)
__device__ __forceinline__ unsigned cvtpk(float lo, float hi) {
  unsigned r;
  asm("v_cvt_pk_bf16_f32 %0, %1, %2" : "=v"(r) : "v"(lo), "v"(hi));
  return r;
}
// fast GELU: x*sigmoid(1.5958(x+0.044715x^3)); |err| ~1e-3 << bf16 quant noise
__device__ __forceinline__ float gelu_f(float v) {
  float v3 = v * v * v;
  float y = 1.5957691216057308f * v + 0.0713548162726009f * v3;
  return v / (1.f + __expf(-y));
}

__device__ __forceinline__ void gload16(const void* g, void* l) {
  __builtin_amdgcn_global_load_lds((const __attribute__((address_space(1))) void*)g,
                                   (__attribute__((address_space(3))) void*)l, 16, 0, 0);
}

// shifted-window mapping: windowed token (b_, n) -> original row index in x
__device__ __forceinline__ int win2orig(int b_, int n) {
  int b = b_ >> 6, wi = b_ & 63;
  int hs = (wi >> 3) * 8 + (n >> 3);
  int ws = (wi & 7) * 8 + (n & 7);
  int hq = (hs + SHIFT_) & 63;
  int wq = (ws + SHIFT_) & 63;
  return b * LL + hq * WWID + wq;
}

// ---------------- tiny setup kernels ----------------
__global__ void cvt_k(const float* __restrict__ s, u16* __restrict__ d, int n) {
  int i = blockIdx.x * 256 + threadIdx.x;
  if (i < n) d[i] = f2bf(s[i]);
}

__global__ void cpb_k(const float* __restrict__ ct, const float* __restrict__ w1,
                      const float* __restrict__ b1, const float* __restrict__ w2,
                      float* __restrict__ t2) {
  int t = blockIdx.x * 256 + threadIdx.x;
  if (t >= 225 * 16) return;
  int rr = t >> 4, h = t & 15;
  float c0 = ct[rr * 2], c1 = ct[rr * 2 + 1];
  float acc = 0.f;
  for (int j = 0; j < 512; j++) {
    float hv = fmaxf(w1[j * 2] * c0 + w1[j * 2 + 1] * c1 + b1[j], 0.f);
    acc += hv * w2[h * 512 + j];
  }
  t2[t] = acc;
}

__global__ void bias_k(const float* __restrict__ t2, const int* __restrict__ rpi,
                       float* __restrict__ b16) {
  int t = blockIdx.x * 256 + threadIdx.x;   // h*4096 + n*64 + m
  int nm = t & 4095;
  int h = t >> 12;
  float v = t2[rpi[nm] * 16 + h];
  b16[t] = 16.0f / (1.0f + __expf(-v));
}

__global__ void scale_k(const float* __restrict__ ls, float* __restrict__ sc) {
  int t = threadIdx.x;
  if (t < HEADS) sc[t] = __expf(fminf(ls[t], 4.6051701859880914f)); // ln(100)
}

// x (fp32) -> xw (bf16) in shifted-window token order [b_*64+n][512]
__global__ __launch_bounds__(256) void xw_k(const float* __restrict__ x, u16* __restrict__ xw) {
  int t = blockIdx.x * 256 + threadIdx.x;
  int row = t >> 6;
  int col = (t & 63) * 8;
  const float* src = x + (size_t)win2orig(row >> 6, row & 63) * CCH + col;
  float4 a = *(const float4*)src;
  float4 b = *(const float4*)(src + 4);
  uint4 o = make_uint4(cvtpk(a.x, a.y), cvtpk(a.z, a.w),
                       cvtpk(b.x, b.y), cvtpk(b.z, b.w));
  *(uint4*)(xw + (size_t)row * CCH + col) = o;
}

// ---------------- MFMA GEMM, 256x128 block tile, 32x32x16 MFMA ----------------
// A bf16 [M][K], B bf16 [N][K] -> C = A @ B^T.  4 waves, wave tile 128x64.
// mfma(b,a): acc holds C^T; lane owns a fixed output row, regs walk N.
// Epilogue: v_permlane32_swap_b32 reassembles the khalf-interleaved 4-channel
//   groups into 8 contiguous channels/lane -> 16B uint4 stores; lane pair
//   (l31, l31+32) covers adjacent 16B -> full 32B sectors per instruction.
// Main loop: depth-2 pipeline, 3 LDS buffers, raw s_barrier + counted
//   s_waitcnt vmcnt(6) (6 gload_lds per tile per thread; never drains to 0
//   in steady state) -> each tile's loads get ~2 compute phases to land.
// LDS swizzle: s(row) = (row + (row>>2)) & 3, chunk c stored at c^s(row).
//   (row&3 alone only covered 4 of 8 bank-quads: row stride 64B = 16 banks,
//    so quads need (row>>2) mixed in; this killed 18.9M conflicts/dispatch.)
// XCD swizzle: lin%8 -> XCD, contiguous M-chunk per XCD for A-tile L2 reuse.
// MODE 0: QKV (epi: +q/v bias, scatter to [b_][h][n][d] bf16)
// MODE 1: proj (epi: +proj_b, bf16 scatter to original token order)
// MODE 2: fc1  (epi: +fc1_b, fast GELU, bf16 ld=HIDN)
// MODE 3: fc2  (epi: +fc2_b, bf16 ld=CCH)
template<int MODE, int NBN>
__global__ __launch_bounds__(256, 2) void gemm256_k(
    const u16* __restrict__ A, const u16* __restrict__ Bw,
    const float* __restrict__ bias,
    const float* __restrict__ qbias, const float* __restrict__ vbias,
    u16* __restrict__ o0, u16* __restrict__ o1, u16* __restrict__ o2,
    int K, int mchunk)
{
  // buf layout: [3][ A:256*32 u16 (16KB) | B:128*32 u16 (8KB) ]  = 72KB total
  __shared__ __align__(16) u16 smem[3 * 12288];
  const int t = threadIdx.x;
  const int lin = blockIdx.x;
  const int xcd = lin & 7;
  const int j = lin >> 3;
  const int m0 = (xcd * mchunk + j / NBN) * 256;
  const int n0 = (j % NBN) * 128;
  const int lane = t & 63;
  const int wv = t >> 6;
  const int wm = (wv & 1) * 128;
  const int wn = (wv >> 1) * 64;
  const int l31 = lane & 31;
  const int khalf = lane >> 5;   // 0/1

  // staging: LDS chunk c = i*256 + t; row = c>>2 = i*64 + (t>>2);
  // s(row) = (row + (row>>2)) & 3 = ((t>>2) + (t>>4)) & 3 for all i.
  const int sstg = (((t >> 2) + (t >> 4)) & 3);
  const int swcol = (((t & 3) ^ sstg) * 8);
  const u16* aP[4]; int aL[4];
  #pragma unroll
  for (int i = 0; i < 4; i++) {
    aP[i] = A + (size_t)(m0 + i * 64 + (t >> 2)) * K + swcol;
    aL[i] = i * 4096 + wv * 1024;
  }
  const u16* bP[2]; int bL[2];
  #pragma unroll
  for (int i = 0; i < 2; i++) {
    bP[i] = Bw + (size_t)(n0 + i * 64 + (t >> 2)) * K + swcol;
    bL[i] = 16384 + i * 4096 + wv * 1024;
  }

  f32x16 acc[4][2] = {};

  auto stage = [&](int k0, int bi) {
    char* base = (char*)smem + bi * 24576;
    #pragma unroll
    for (int i = 0; i < 4; i++) gload16(aP[i] + k0, base + aL[i]);
    #pragma unroll
    for (int i = 0; i < 2; i++) gload16(bP[i] + k0, base + bL[i]);
  };

  const int NT = K >> 5;
  // prologue: stage tiles 0 and 1
  stage(0, 0);
  stage(32, 1);

  // read-side swizzle: row = wm|wn + mt*32 + l31 (tile bases are mult. of 16)
  const int srd = ((l31 & 3) + ((l31 >> 2) & 3)) & 3;

  for (int it = 0; it < NT; ++it) {
    // own tile-it loads complete (oldest); tile it+1 may stay in flight
    if (it + 1 < NT) asm volatile("s_waitcnt vmcnt(6)" ::: "memory");
    else             asm volatile("s_waitcnt vmcnt(0)" ::: "memory");
    __builtin_amdgcn_s_barrier();       // all waves: tile it ready; reads of it-1 done
    asm volatile("" ::: "memory");      // keep ds_reads below the barrier
    if (it + 2 < NT) stage((it + 2) << 5, (it + 2) % 3);

    const u16* Ab = (const u16*)((const char*)smem + (it % 3) * 24576);
    const u16* Bb = Ab + 8192;
    #pragma unroll
    for (int ks = 0; ks < 2; ks++) {
      const int kc = (ks * 2 + khalf) ^ srd;   // swizzled k-chunk
      bf16x8 af[4], bf[2];
      #pragma unroll
      for (int mt = 0; mt < 4; mt++)
        af[mt] = *(const bf16x8*)&Ab[(wm + mt * 32 + l31) * 32 + kc * 8];
      #pragma unroll
      for (int nt = 0; nt < 2; nt++)
        bf[nt] = *(const bf16x8*)&Bb[(wn + nt * 32 + l31) * 32 + kc * 8];
      #pragma unroll
      for (int mt = 0; mt < 4; mt++)
        #pragma unroll
        for (int nt = 0; nt < 2; nt++)
          acc[mt][nt] = __builtin_amdgcn_mfma_f32_32x32x16_bf16(bf[nt], af[mt], acc[mt][nt], 0, 0, 0);
    }
    // next iteration's barrier protects buffer reuse
  }

  // epilogue: acc holds C^T tiles.
  //   row = m0+wm+mt*32+l31 (fixed/lane); own cols = cb + 8g + 4*khalf (+0..3)
  // permlane32_swap(U_g, U_{g+1}): lane assembles 8 contiguous channels;
  // khalf pair covers a full 32B-aligned sector.
  const int part = n0 >> 9;   // MODE 0 only (tile never spans q/k/v parts)
  u16* qkvdst = (MODE == 0) ? (part == 0 ? o0 : (part == 1 ? o1 : o2)) : o0;
  #pragma unroll
  for (int mt = 0; mt < 4; mt++) {
    const int grow = m0 + wm + mt * 32 + l31;
    size_t rowbase;
    if (MODE == 0) {
      int b_ = grow >> 6, n = grow & 63;
      rowbase = ((size_t)b_ * HEADS) * (NTOK * DDIM) + (size_t)n * DDIM;
    } else if (MODE == 1) {
      rowbase = (size_t)win2orig(grow >> 6, grow & 63) * CCH;
    } else if (MODE == 2) {
      rowbase = (size_t)grow * HIDN;
    } else {
      rowbase = (size_t)grow * CCH;
    }
    #pragma unroll
    for (int nt = 0; nt < 2; nt++) {
      const int cb = n0 + wn + nt * 32;          // 32-aligned channel base
      unsigned U[4], W[4];
      #pragma unroll
      for (int g = 0; g < 4; g++) {
        const int nb = cb + 8 * g + 4 * khalf;
        float v0 = acc[mt][nt][g * 4 + 0];
        float v1 = acc[mt][nt][g * 4 + 1];
        float v2 = acc[mt][nt][g * 4 + 2];
        float v3 = acc[mt][nt][g * 4 + 3];
        if (MODE == 0) {
          const int cc = nb & 511;
          if (part == 0) {
            float4 b4 = *(const float4*)(qbias + cc);
            v0 += b4.x; v1 += b4.y; v2 += b4.z; v3 += b4.w;
          } else if (part == 2) {
            float4 b4 = *(const float4*)(vbias + cc);
            v0 += b4.x; v1 += b4.y; v2 += b4.z; v3 += b4.w;
          }
        } else {
          float4 b4 = *(const float4*)(bias + nb);
          v0 += b4.x; v1 += b4.y; v2 += b4.z; v3 += b4.w;
          if (MODE == 2) {
            v0 = gelu_f(v0); v1 = gelu_f(v1); v2 = gelu_f(v2); v3 = gelu_f(v3);
          }
        }
        U[g] = cvtpk(v0, v1);
        W[g] = cvtpk(v2, v3);
      }
      // A.high <-> B.low swaps: assemble 8 contiguous channels per lane
      asm volatile("v_permlane32_swap_b32 %0, %1" : "+v"(U[0]), "+v"(U[1]));
      asm volatile("v_permlane32_swap_b32 %0, %1" : "+v"(W[0]), "+v"(W[1]));
      asm volatile("v_permlane32_swap_b32 %0, %1" : "+v"(U[2]), "+v"(U[3]));
      asm volatile("v_permlane32_swap_b32 %0, %1" : "+v"(W[2]), "+v"(W[3]));
      uint4 s1 = make_uint4(U[0], W[0], U[1], W[1]);   // cols [cb+8k, cb+8k+8)
      uint4 s2 = make_uint4(U[2], W[2], U[3], W[3]);   // cols [cb+16+8k, +8)
      if (MODE == 0) {
        const int cc1 = (cb & 511) + 8 * khalf;
        const int cc2 = cc1 + 16;
        *(uint4*)(qkvdst + rowbase + (size_t)(cc1 >> 5) * (NTOK * DDIM) + (cc1 & 31)) = s1;
        *(uint4*)(qkvdst + rowbase + (size_t)(cc2 >> 5) * (NTOK * DDIM) + (cc2 & 31)) = s2;
      } else {
        *(uint4*)(o0 + rowbase + cb + 8 * khalf) = s1;
        *(uint4*)(o0 + rowbase + cb + 16 + 8 * khalf) = s2;
      }
    }
  }
}

// ---------------- attention: one wave per (window, head), in-register softmax ----------------
__global__ __launch_bounds__(64) void attn_k(
    const u16* __restrict__ qb, const u16* __restrict__ kb, const u16* __restrict__ vb,
    const float* __restrict__ bias16, const float* __restrict__ scale,
    const float* __restrict__ amask, u16* __restrict__ attn_out)
{
  __shared__ u16 Pmat[64][72];   // bf16 P (unnormalized), 144B rows (16B-aligned)
  __shared__ u16 vT[32][72];     // V transposed [d][tok]

  int bh = blockIdx.x;
  int b_ = bh >> 4, h = bh & 15;
  int wi = b_ & 63;
  int lane = threadIdx.x;
  int l15 = lane & 15, quad = lane >> 4;
  const u16* qs = qb + (size_t)bh * (NTOK * DDIM);
  const u16* ks = kb + (size_t)bh * (NTOK * DDIM);
  const u16* vs = vb + (size_t)bh * (NTOK * DDIM);

  bf16x8 qf[4], kf[4];
  #pragma unroll
  for (int mt = 0; mt < 4; mt++) {
    qf[mt] = *(const bf16x8*)(qs + (mt * 16 + l15) * DDIM + quad * 8);
    kf[mt] = *(const bf16x8*)(ks + (mt * 16 + l15) * DDIM + quad * 8);
  }
  // fused cosine normalization: lanes {l15, +16, +32, +48} share a row
  #pragma unroll
  for (int mt = 0; mt < 4; mt++) {
    float sq = 0.f, sk = 0.f;
    #pragma unroll
    for (int jj = 0; jj < 8; jj++) {
      float a = bf2f((u16)qf[mt][jj]); sq += a * a;
      float b = bf2f((u16)kf[mt][jj]); sk += b * b;
    }
    sq += __shfl_xor(sq, 16); sq += __shfl_xor(sq, 32);
    sk += __shfl_xor(sk, 16); sk += __shfl_xor(sk, 32);
    float iq = 1.f / fmaxf(sqrtf(sq), 1e-12f);
    float ik = 1.f / fmaxf(sqrtf(sk), 1e-12f);
    #pragma unroll
    for (int jj = 0; jj < 8; jj++) {
      qf[mt][jj] = (short)f2bf(bf2f((u16)qf[mt][jj]) * iq);
      kf[mt][jj] = (short)f2bf(bf2f((u16)kf[mt][jj]) * ik);
    }
  }
  // S = qn @ kn^T (in registers)
  f32x4 s[4][4];
  #pragma unroll
  for (int mt = 0; mt < 4; mt++)
    #pragma unroll
    for (int nt = 0; nt < 4; nt++) {
      f32x4 c = {0.f, 0.f, 0.f, 0.f};
      s[mt][nt] = __builtin_amdgcn_mfma_f32_16x16x32_bf16(qf[mt], kf[nt], c, 0, 0, 0);
    }
  // stage V^T
  #pragma unroll
  for (int d8 = 0; d8 < 4; d8++) {
    bf16x8 vv = *(const bf16x8*)(vs + lane * DDIM + d8 * 8);
    #pragma unroll
    for (int jj = 0; jj < 8; jj++) vT[d8 * 8 + jj][lane] = (u16)vv[jj];
  }

  // in-register softmax: row = mt*16+quad*4+i (16 lanes/row across l15)
  float sc = scale[h];
  float rinv[4][4];
  const float* bbase = bias16 + (size_t)h * 4096;
  const float* mbase = amask + (size_t)wi * 4096;
  #pragma unroll
  for (int mt = 0; mt < 4; mt++) {
    #pragma unroll
    for (int i = 0; i < 4; i++) {
      int row = mt * 16 + quad * 4 + i;
      const float* bro = bbase + row * 64;
      const float* mro = mbase + row * 64;
      float p[4];
      float mx = -1e30f;
      #pragma unroll
      for (int nt = 0; nt < 4; nt++) {
        int col = nt * 16 + l15;
        float vv = s[mt][nt][i] * sc + bro[col] + mro[col];
        p[nt] = vv;
        mx = fmaxf(mx, vv);
      }
      mx = fmaxf(mx, __shfl_xor(mx, 1));
      mx = fmaxf(mx, __shfl_xor(mx, 2));
      mx = fmaxf(mx, __shfl_xor(mx, 4));
      mx = fmaxf(mx, __shfl_xor(mx, 8));
      float sum = 0.f;
      #pragma unroll
      for (int nt = 0; nt < 4; nt++) {
        float e = __expf(p[nt] - mx);
        p[nt] = e;
        sum += e;
      }
      sum += __shfl_xor(sum, 1);
      sum += __shfl_xor(sum, 2);
      sum += __shfl_xor(sum, 4);
      sum += __shfl_xor(sum, 8);
      rinv[mt][i] = 1.f / sum;
      #pragma unroll
      for (int nt = 0; nt < 4; nt++)
        Pmat[row][nt * 16 + l15] = f2bf(p[nt]);
    }
  }
  __syncthreads();

  // O = P @ V (1/sum folded into epilogue)
  f32x4 oacc[4][2] = {};
  #pragma unroll
  for (int ks2 = 0; ks2 < 2; ks2++) {
    bf16x8 pf[4], vf[2];
    #pragma unroll
    for (int mt = 0; mt < 4; mt++)
      pf[mt] = *(const bf16x8*)&Pmat[mt * 16 + l15][ks2 * 32 + quad * 8];
    #pragma unroll
    for (int nt = 0; nt < 2; nt++)
      vf[nt] = *(const bf16x8*)&vT[nt * 16 + l15][ks2 * 32 + quad * 8];
    #pragma unroll
    for (int mt = 0; mt < 4; mt++)
      #pragma unroll
      for (int nt = 0; nt < 2; nt++)
        oacc[mt][nt] = __builtin_amdgcn_mfma_f32_16x16x32_bf16(pf[mt], vf[nt], oacc[mt][nt], 0, 0, 0);
  }
  #pragma unroll
  for (int mt = 0; mt < 4; mt++)
    #pragma unroll
    for (int nt = 0; nt < 2; nt++)
      #pragma unroll
      for (int i = 0; i < 4; i++) {
        int n = mt * 16 + quad * 4 + i;
        int d = nt * 16 + l15;
        float val = oacc[mt][nt][i] * rinv[mt][i];
        attn_out[(size_t)(b_ * 64 + n) * CCH + h * DDIM + d] = f2bf(val);
      }
}

// ---------------- LayerNorm + residual kernels (one wave per row) ----------------
__global__ __launch_bounds__(256) void ln_res_k(
    const float* __restrict__ xin, const u16* __restrict__ pin,
    const float* __restrict__ gam, const float* __restrict__ bet,
    float* __restrict__ x1f, u16* __restrict__ x1b)
{
  int row = blockIdx.x * 4 + (threadIdx.x >> 6);
  int lane = threadIdx.x & 63;
  size_t base = (size_t)row * CCH + lane * 8;
  uint4 u = *(const uint4*)(pin + base);
  unsigned w[4] = {u.x, u.y, u.z, u.w};
  float pv[8];
  #pragma unroll
  for (int j = 0; j < 4; j++) {
    pv[j * 2] = bf2f(w[j] & 0xffffu);
    pv[j * 2 + 1] = bf2f(w[j] >> 16);
  }
  float4 x0 = *(const float4*)(xin + base);
  float4 x1 = *(const float4*)(xin + base + 4);
  float xr[8] = {x0.x, x0.y, x0.z, x0.w, x1.x, x1.y, x1.z, x1.w};
  float s = 0.f, sq = 0.f;
  #pragma unroll
  for (int j = 0; j < 8; j++) { s += pv[j]; sq += pv[j] * pv[j]; }
  #pragma unroll
  for (int o = 32; o > 0; o >>= 1) { s += __shfl_xor(s, o, 64); sq += __shfl_xor(sq, o, 64); }
  float mean = s * (1.0f / 512.0f);
  float var = sq * (1.0f / 512.0f) - mean * mean;
  float rstd = rsqrtf(var + 1e-5f);
  float4 g0 = *(const float4*)(gam + lane * 8);
  float4 g1 = *(const float4*)(gam + lane * 8 + 4);
  float4 b0 = *(const float4*)(bet + lane * 8);
  float4 b1 = *(const float4*)(bet + lane * 8 + 4);
  float gg[8] = {g0.x, g0.y, g0.z, g0.w, g1.x, g1.y, g1.z, g1.w};
  float bb[8] = {b0.x, b0.y, b0.z, b0.w, b1.x, b1.y, b1.z, b1.w};
  float val[8];
  #pragma unroll
  for (int j = 0; j < 8; j++)
    val[j] = xr[j] + (pv[j] - mean) * rstd * gg[j] + bb[j];
  *(float4*)(x1f + base)     = make_float4(val[0], val[1], val[2], val[3]);
  *(float4*)(x1f + base + 4) = make_float4(val[4], val[5], val[6], val[7]);
  *(uint4*)(x1b + base) = make_uint4(cvtpk(val[0], val[1]), cvtpk(val[2], val[3]),
                                     cvtpk(val[4], val[5]), cvtpk(val[6], val[7]));
}

__global__ __launch_bounds__(256) void ln_fin_k(
    const u16* __restrict__ mlp, const float* __restrict__ gam,
    const float* __restrict__ bet, float* __restrict__ io)
{
  int row = blockIdx.x * 4 + (threadIdx.x >> 6);
  int lane = threadIdx.x & 63;
  size_t base = (size_t)row * CCH + lane * 8;
  uint4 u = *(const uint4*)(mlp + base);
  unsigned w[4] = {u.x, u.y, u.z, u.w};
  float pv[8];
  #pragma unroll
  for (int j = 0; j < 4; j++) {
    pv[j * 2] = bf2f(w[j] & 0xffffu);
    pv[j * 2 + 1] = bf2f(w[j] >> 16);
  }
  float s = 0.f, sq = 0.f;
  #pragma unroll
  for (int j = 0; j < 8; j++) { s += pv[j]; sq += pv[j] * pv[j]; }
  #pragma unroll
  for (int o = 32; o > 0; o >>= 1) { s += __shfl_xor(s, o, 64); sq += __shfl_xor(sq, o, 64); }
  float mean = s * (1.0f / 512.0f);
  float var = sq * (1.0f / 512.0f) - mean * mean;
  float rstd = rsqrtf(var + 1e-5f);
  float4 g0 = *(const float4*)(gam + lane * 8);
  float4 g1 = *(const float4*)(gam + lane * 8 + 4);
  float4 b0 = *(const float4*)(bet + lane * 8);
  float4 b1 = *(const float4*)(bet + lane * 8 + 4);
  float gg[8] = {g0.x, g0.y, g0.z, g0.w, g1.x, g1.y, g1.z, g1.w};
  float bb[8] = {b0.x, b0.y, b0.z, b0.w, b1.x, b1.y, b1.z, b1.w};
  float4 i0 = *(const float4*)(io + base);
  float4 i1 = *(const float4*)(io + base + 4);
  float iv[8] = {i0.x, i0.y, i0.z, i0.w, i1.x, i1.y, i1.z, i1.w};
  float out[8];
  #pragma unroll
  for (int j = 0; j < 8; j++)
    out[j] = iv[j] + (pv[j] - mean) * rstd * gg[j] + bb[j];
  *(float4*)(io + base)     = make_float4(out[0], out[1], out[2], out[3]);
  *(float4*)(io + base + 4) = make_float4(out[4], out[5], out[6], out[7]);
}

// ---------------- launcher ----------------
#define OFF_Q     ((size_t)0)
#define OFF_K     ((size_t)67108864)
#define OFF_V     ((size_t)134217728)
#define OFF_ATTN  ((size_t)201326592)
#define OFF_X1B   ((size_t)268435456)
#define OFF_WQKV  ((size_t)335544320)
#define OFF_WPROJ ((size_t)337117184)
#define OFF_WFC1  ((size_t)337641472)
#define OFF_WFC2  ((size_t)339738624)
#define OFF_T2    ((size_t)341835776)
#define OFF_B16   ((size_t)341852160)
#define OFF_SC    ((size_t)342114304)

extern "C" void kernel_launch(void* const* d_in, const int* in_sizes, int n_in,
                              void* d_out, int out_size, void* d_ws, size_t ws_size,
                              hipStream_t stream) {
  const float* x        = (const float*)d_in[0];
  const float* qkv_w    = (const float*)d_in[1];
  const float* q_bias   = (const float*)d_in[2];
  const float* v_bias   = (const float*)d_in[3];
  const float* lscale   = (const float*)d_in[4];
  const float* cpb_w1   = (const float*)d_in[5];
  const float* cpb_b1   = (const float*)d_in[6];
  const float* cpb_w2   = (const float*)d_in[7];
  const float* proj_w   = (const float*)d_in[8];
  const float* proj_b   = (const float*)d_in[9];
  const float* n1g      = (const float*)d_in[10];
  const float* n1b      = (const float*)d_in[11];
  const float* n2g      = (const float*)d_in[12];
  const float* n2b      = (const float*)d_in[13];
  const float* fc1_w    = (const float*)d_in[14];
  const float* fc1_b    = (const float*)d_in[15];
  const float* fc2_w    = (const float*)d_in[16];
  const float* fc2_b    = (const float*)d_in[17];
  const float* ctab     = (const float*)d_in[18];
  const float* amask    = (const float*)d_in[19];
  const int*   rpi      = (const int*)d_in[20];

  char* ws = (char*)d_ws;
  float* outp = (float*)d_out;

  u16*   q_buf    = (u16*)(ws + OFF_Q);
  u16*   k_buf    = (u16*)(ws + OFF_K);
  u16*   v_buf    = (u16*)(ws + OFF_V);
  u16*   proj_out = (u16*)(ws + OFF_Q);     // reuse R0 (bf16 now)
  u16*   hid      = (u16*)(ws + OFF_Q);     // reuse R0 (half-batch)
  u16*   xw       = (u16*)(ws + OFF_ATTN);  // R1 (dead after QKV gemm)
  u16*   attn_out = (u16*)(ws + OFF_ATTN);
  u16*   mlp_out  = (u16*)(ws + OFF_ATTN);
  u16*   x1b      = (u16*)(ws + OFF_X1B);
  u16*   wqkv     = (u16*)(ws + OFF_WQKV);
  u16*   wproj    = (u16*)(ws + OFF_WPROJ);
  u16*   wfc1     = (u16*)(ws + OFF_WFC1);
  u16*   wfc2     = (u16*)(ws + OFF_WFC2);
  float* t2       = (float*)(ws + OFF_T2);
  float* b16      = (float*)(ws + OFF_B16);
  float* scbuf    = (float*)(ws + OFF_SC);

  cvt_k<<<(1536 * 512 + 255) / 256, 256, 0, stream>>>(qkv_w, wqkv, 1536 * 512);
  cvt_k<<<(512 * 512 + 255) / 256, 256, 0, stream>>>(proj_w, wproj, 512 * 512);
  cvt_k<<<(2048 * 512 + 255) / 256, 256, 0, stream>>>(fc1_w, wfc1, 2048 * 512);
  cvt_k<<<(512 * 2048 + 255) / 256, 256, 0, stream>>>(fc2_w, wfc2, 512 * 2048);
  cpb_k<<<15, 256, 0, stream>>>(ctab, cpb_w1, cpb_b1, cpb_w2, t2);
  bias_k<<<256, 256, 0, stream>>>(t2, rpi, b16);
  scale_k<<<1, 64, 0, stream>>>(lscale, scbuf);

  // x -> xw (bf16, shifted-window order)
  xw_k<<<MTOT * 64 / 256, 256, 0, stream>>>(x, xw);
  // QKV: M=65536 (256 m-tiles), N=1536 (12 n-tiles)
  gemm256_k<0, 12><<<256 * 12, 256, 0, stream>>>(
      xw, wqkv, nullptr, q_bias, v_bias, q_buf, k_buf, v_buf, 512, 32);
  // attention (fused cosine norm, in-register softmax)
  attn_k<<<BWIN * HEADS, 64, 0, stream>>>(q_buf, k_buf, v_buf, b16, scbuf, amask, attn_out);
  // proj: N=512 (4 n-tiles), bf16 out, window-reverse fused
  gemm256_k<1, 4><<<256 * 4, 256, 0, stream>>>(
      attn_out, wproj, proj_b, nullptr, nullptr, proj_out, nullptr, nullptr, 512, 32);
  // x1 = x + LN1(proj_out)
  ln_res_k<<<MTOT / 4, 256, 0, stream>>>(x, proj_out, n1g, n1b, outp, x1b);
  // MLP in two row-halves
  for (int half = 0; half < 2; half++) {
    const u16* a1 = x1b + (size_t)half * (MTOT / 2) * CCH;
    u16* m1 = mlp_out + (size_t)half * (MTOT / 2) * CCH;
    gemm256_k<2, 16><<<128 * 16, 256, 0, stream>>>(
        a1, wfc1, fc1_b, nullptr, nullptr, hid, nullptr, nullptr, 512, 16);
    gemm256_k<3, 4><<<128 * 4, 256, 0, stream>>>(
        hid, wfc2, fc2_b, nullptr, nullptr, m1, nullptr, nullptr, 2048, 16);
  }
  // out = x1 + LN2(mlp)
  ln_fin_k<<<MTOT / 4, 256, 0, stream>>>(mlp_out, n2g, n2b, outp);
}